// Round 9
// baseline (149.232 us; speedup 1.0000x reference)
//
#include <hip/hip_runtime.h>
#include <math.h>

// B=128, NU=32, NT=64, H=128, OUT_F=16, N_U=4096, N_A=8192
// Per-batch-local GNN (graph fully bipartite within batch; all segment-means
// are per-batch means). R9 structure:
//   128 blocks x 1024 threads (16 waves) -- ONE BLOCK PER BATCH.
//   Block owns all 32 hu + 64 ha rows in LDS end-to-end: ZERO inter-block
//   syncs after the weight-prep flag barrier (R8 still had 3 pairwise MALL
//   round-trip syncs + partial exchanges).
//   Waves: n-split 8 (16 cols each) x m-split 2. 4 waves/SIMD.
//   A-frag software pipeline: each stage prefetches the NEXT stage's weight
//   fragments before issuing its MFMAs -- the per-stage 200-600cy global
//   weight-load leaves the critical path (R8 paid it every stage).
// Weights pre-transposed [n][k] by 104 prep units + flag barrier (relaxed
// atomics only; sc1 write-through + first-touch-after-barrier coherence).

using frag  = __attribute__((ext_vector_type(8))) short;   // 8 x bf16
using f32x4 = __attribute__((ext_vector_type(4))) float;

#define LDST 136
#define SCOPE_AGT __HIP_MEMORY_SCOPE_AGENT

__device__ __forceinline__ float  bf2f(ushort u) { return __uint_as_float(((unsigned)u) << 16); }
__device__ __forceinline__ ushort f2bf(float f) {
    unsigned u = __float_as_uint(f);
    u += 0x7fff + ((u >> 16) & 1);            // RNE
    return (ushort)(u >> 16);
}
__device__ __forceinline__ void gst4_sc(void* p, unsigned v) {   // write-through to MALL
    asm volatile("global_store_dword %0, %1, off sc1" :: "v"(p), "v"(v) : "memory");
}

struct GP {
    const float *uf, *noise, *b_ue, *W_t, *b_t;
    const float *wsrc[13];    // fp32 weights for prep; slot 12 = W_ue
    const float *bias6[6];    // ca_aggr_b, ca_self_b, ca_comb_b, cu_aggr_b, cu_self_b, cu_comb_b
    const float *Wn, *bn;
    float *out;
    ushort *WtAll;            // 13 x [128][128] bf16 (n-major)
    unsigned *cnt;
};
// WtAll slots: 0,1 ca_aggr; 2,3 ca_self; 4,5 ca_comb; 6,7 cu_aggr;
//              8,9 cu_self; 10,11 cu_comb; 12 W_ue

struct AF { frag f[4]; };
__device__ __forceinline__ AF loadA(const ushort* __restrict__ Wt, int n0, int l15, int q) {
    AF r;
#pragma unroll
    for (int kc = 0; kc < 4; ++kc)
        r.f[kc] = *(const frag*)(Wt + (n0 + l15) * 128 + kc * 32 + q * 8);
    return r;
}

// ---- MLP stage: wave (n8,mg) computes cols [16n8,16n8+16) x its m-tiles ----
template<int MT, bool MEANADD>
__device__ __forceinline__ void mlp_stage(const AF& A, const ushort* Xl, ushort* Yl,
    const float* __restrict__ bias, const float* meanL, int n0, int l15, int q, int mg)
{
    const float4 bv = *(const float4*)(bias + n0 + q * 4);
    float4 mv = {0.f, 0.f, 0.f, 0.f};
    if (MEANADD) mv = *(const float4*)(meanL + n0 + q * 4);
#pragma unroll
    for (int i = 0; i < MT / 2; ++i) {
        const int mt = mg * (MT / 2) + i;
        frag Bv[4];
#pragma unroll
        for (int kc = 0; kc < 4; ++kc)
            Bv[kc] = *(const frag*)(Xl + (mt * 16 + l15) * LDST + kc * 32 + q * 8);
        f32x4 acc = {0.f, 0.f, 0.f, 0.f};
#pragma unroll
        for (int kc = 0; kc < 4; ++kc)
            acc = __builtin_amdgcn_mfma_f32_16x16x32_bf16(A.f[kc], Bv[kc], acc, 0, 0, 0);
        float v0 = acc[0] + bv.x, v1 = acc[1] + bv.y, v2 = acc[2] + bv.z, v3 = acc[3] + bv.w;
        v0 = v0 > 0.f ? v0 : 0.f; v1 = v1 > 0.f ? v1 : 0.f;
        v2 = v2 > 0.f ? v2 : 0.f; v3 = v3 > 0.f ? v3 : 0.f;
        if (MEANADD) { v0 += mv.x; v1 += mv.y; v2 += mv.z; v3 += mv.w; }
        ushort4 o = { f2bf(v0), f2bf(v1), f2bf(v2), f2bf(v3) };
        *(ushort4*)(Yl + (mt * 16 + l15) * LDST + n0 + q * 4) = o;
    }
}

// ---- column mean over ROWS rows -> dst[128] (all-LDS; scale = 1/deg) ----
template<int ROWS>
__device__ __forceinline__ void colmean(const ushort* buf, float* redL, float* dst, float scale) {
    const int t = threadIdx.x;
    if (t < 512) {
        const int g4 = t >> 7, col = t & 127;
        float s = 0.f;
#pragma unroll
        for (int r = g4; r < ROWS; r += 4) s += bf2f(buf[r * LDST + col]);
        redL[g4 * 128 + col] = s;
    }
    __syncthreads();
    if (t < 128) dst[t] = (redL[t] + redL[128 + t] + redL[256 + t] + redL[384 + t]) * scale;
    __syncthreads();
}

// ---- weight transpose: fp32 [k][n] -> bf16 [n][k], one 16-k slab (1024 thr) ----
__device__ __forceinline__ void wslab(ushort* dst, float* slab,
                                      const float* __restrict__ W, int kb)
{
    if (threadIdx.x < 512) {
        const int c = threadIdx.x;              // 16 rows x 32 float4
        const int kr = c >> 5, c4 = c & 31;
        const float4 v = *(const float4*)(W + (kb * 16 + kr) * 128 + c4 * 4);
        slab[kr * 129 + c4 * 4 + 0] = v.x; slab[kr * 129 + c4 * 4 + 1] = v.y;
        slab[kr * 129 + c4 * 4 + 2] = v.z; slab[kr * 129 + c4 * 4 + 3] = v.w;
    }
    __syncthreads();
    {
        const int c = threadIdx.x;              // 128 n x 8 k-pairs = 1024
        const int n = c >> 3, k2 = c & 7;
        const unsigned d = (unsigned)f2bf(slab[(2 * k2) * 129 + n])
                         | ((unsigned)f2bf(slab[(2 * k2 + 1) * 129 + n]) << 16);
        gst4_sc(dst + n * 128 + kb * 16 + 2 * k2, d);
    }
    __syncthreads();
}

__global__ __launch_bounds__(1024, 1) void k_gnn(GP P)
{
    __shared__ __align__(16) ushort HU[32 * LDST];   // hu -> (aliased) hu2
    __shared__ __align__(16) ushort HA[64 * LDST];   // ha -> (aliased) ha2
    __shared__ __align__(16) ushort T0[64 * LDST];
    __shared__ __align__(16) ushort T1[64 * LDST];
    __shared__ float redL[512], mA[128], mB[128];

    const int b = blockIdx.x, tid = threadIdx.x;
    const int lane = tid & 63, wave = tid >> 6;
    const int q = lane >> 4, l15 = lane & 15;
    const int n0 = (wave & 7) * 16, mg = wave >> 3;
    const ushort* Wt = P.WtAll;
    const float* const* bb = P.bias6;

    // ---- weight prep (104 of 128 blocks; slab temp in T1) ----
    if (b < 104)
        wslab(P.WtAll + (b >> 3) * 16384, (float*)T1, P.wsrc[b >> 3], b & 7);

    // stage own 32 uf rows -> T0 (1024 chunks exactly)
    {
        const int r = tid >> 5, k4 = tid & 31;
        const float4 v = *(const float4*)(P.uf + (size_t)(b * 32 + r) * 128 + k4 * 4);
        ushort4 o = { f2bf(v.x), f2bf(v.y), f2bf(v.z), f2bf(v.w) };
        *(ushort4*)(T0 + r * LDST + k4 * 4) = o;
    }
    // stage own 64 noise rows -> HA (ant added later)
#pragma unroll
    for (int c = tid; c < 2048; c += 1024) {
        const int r = c >> 5, k4 = c & 31;
        const float4 v = *(const float4*)(P.noise + (size_t)(b * 64 + r) * 128 + k4 * 4);
        ushort4 o = { f2bf(v.x), f2bf(v.y), f2bf(v.z), f2bf(v.w) };
        *(ushort4*)(HA + r * LDST + k4 * 4) = o;
    }

    // ---- prep flag barrier: last arriver broadcasts ----
    asm volatile("s_waitcnt vmcnt(0)" ::: "memory");
    __syncthreads();
    if (tid == 0) {
        if (b < 104) {
            unsigned old = __hip_atomic_fetch_add(P.cnt, 1u, __ATOMIC_RELAXED, SCOPE_AGT);
            if (old == 103u) __hip_atomic_store(P.cnt + 32, 1u, __ATOMIC_RELAXED, SCOPE_AGT);
        }
        while (__hip_atomic_load(P.cnt + 32, __ATOMIC_RELAXED, SCOPE_AGT) < 1u)
            __builtin_amdgcn_s_sleep(4);
    }
    __syncthreads();

    AF A, An = loadA(Wt + 12 * 16384, n0, l15, q);

    // S1: embed  uf->HU
    A = An; An = loadA(Wt + 0 * 16384, n0, l15, q);
    mlp_stage<2, false>(A, T0, HU, P.b_ue, nullptr, n0, l15, q, mg);
    __syncthreads();
    colmean<32>(HU, redL, mA, 1.f / 32.f);                 // mA = meanE
    // ant = relu(meanE @ W_t + b_t) -> mB; HA += ant
    if (tid < 512) {
        const int g4 = tid >> 7, col = tid & 127;
        float s = 0.f;
#pragma unroll 4
        for (int k = g4 * 32; k < g4 * 32 + 32; ++k) s += mA[k] * P.W_t[k * 128 + col];
        redL[g4 * 128 + col] = s;
    }
    __syncthreads();
    if (tid < 128) {
        float a = P.b_t[tid] + redL[tid] + redL[128 + tid] + redL[256 + tid] + redL[384 + tid];
        mB[tid] = a > 0.f ? a : 0.f;
    }
    __syncthreads();
#pragma unroll
    for (int c = tid; c < 2048; c += 1024) {
        const int r = c >> 5, k4 = c & 31;
        ushort4 h = *(ushort4*)(HA + r * LDST + k4 * 4);
        ushort4 o = { f2bf(bf2f(h.x) + mB[k4 * 4 + 0]), f2bf(bf2f(h.y) + mB[k4 * 4 + 1]),
                      f2bf(bf2f(h.z) + mB[k4 * 4 + 2]), f2bf(bf2f(h.w) + mB[k4 * 4 + 3]) };
        *(ushort4*)(HA + r * LDST + k4 * 4) = o;
    }
    __syncthreads();

    // S2-S3: it0 aggr-hu (ca_aggr) + meanA0
    A = An; An = loadA(Wt + 1 * 16384, n0, l15, q);
    mlp_stage<2, false>(A, HU, T0, bb[0], nullptr, n0, l15, q, mg);
    __syncthreads();
    A = An; An = loadA(Wt + 6 * 16384, n0, l15, q);
    mlp_stage<2, false>(A, T0, T1, bb[0] + 128, nullptr, n0, l15, q, mg);
    __syncthreads();
    colmean<32>(T1, redL, mA, 1.f / 32.f);                 // mA = meanA0

    // S4-S5: it0 aggr-ha (cu_aggr) + meanU0
    A = An; An = loadA(Wt + 7 * 16384, n0, l15, q);
    mlp_stage<4, false>(A, HA, T0, bb[3], nullptr, n0, l15, q, mg);
    __syncthreads();
    A = An; An = loadA(Wt + 2 * 16384, n0, l15, q);
    mlp_stage<4, false>(A, T0, T1, bb[3] + 128, nullptr, n0, l15, q, mg);
    __syncthreads();
    colmean<64>(T1, redL, mB, 1.f / 64.f);                 // mB = meanU0

    // S6-S9: it0 comb-ha  (self2 + meanA0 -> comb2) ; HA := ha2
    A = An; An = loadA(Wt + 3 * 16384, n0, l15, q);
    mlp_stage<4, false>(A, HA, T0, bb[1], nullptr, n0, l15, q, mg);
    __syncthreads();
    A = An; An = loadA(Wt + 4 * 16384, n0, l15, q);
    mlp_stage<4, true >(A, T0, T1, bb[1] + 128, mA, n0, l15, q, mg);
    __syncthreads();
    A = An; An = loadA(Wt + 5 * 16384, n0, l15, q);
    mlp_stage<4, false>(A, T1, T0, bb[2], nullptr, n0, l15, q, mg);
    __syncthreads();
    A = An; An = loadA(Wt + 8 * 16384, n0, l15, q);
    mlp_stage<4, false>(A, T0, HA, bb[2] + 128, nullptr, n0, l15, q, mg);
    __syncthreads();

    // S10-S13: it0 comb-hu ; HU := hu2
    A = An; An = loadA(Wt + 9 * 16384, n0, l15, q);
    mlp_stage<2, false>(A, HU, T0, bb[4], nullptr, n0, l15, q, mg);
    __syncthreads();
    A = An; An = loadA(Wt + 10 * 16384, n0, l15, q);
    mlp_stage<2, true >(A, T0, T1, bb[4] + 128, mB, n0, l15, q, mg);
    __syncthreads();
    A = An; An = loadA(Wt + 11 * 16384, n0, l15, q);
    mlp_stage<2, false>(A, T1, T0, bb[5], nullptr, n0, l15, q, mg);
    __syncthreads();
    A = An; An = loadA(Wt + 0 * 16384, n0, l15, q);
    mlp_stage<2, false>(A, T0, HU, bb[5] + 128, nullptr, n0, l15, q, mg);
    __syncthreads();

    // S14-S15: it1 aggr-hu2 + meanA1  (it1 cu-side is dead)
    A = An; An = loadA(Wt + 1 * 16384, n0, l15, q);
    mlp_stage<2, false>(A, HU, T0, bb[0], nullptr, n0, l15, q, mg);
    __syncthreads();
    A = An; An = loadA(Wt + 2 * 16384, n0, l15, q);
    mlp_stage<2, false>(A, T0, T1, bb[0] + 128, nullptr, n0, l15, q, mg);
    __syncthreads();
    colmean<32>(T1, redL, mA, 1.f / 32.f);                 // mA = meanA1

    // S16-S19: it1 comb-ha2 -> T1
    A = An; An = loadA(Wt + 3 * 16384, n0, l15, q);
    mlp_stage<4, false>(A, HA, T0, bb[1], nullptr, n0, l15, q, mg);
    __syncthreads();
    A = An; An = loadA(Wt + 4 * 16384, n0, l15, q);
    mlp_stage<4, true >(A, T0, T1, bb[1] + 128, mA, n0, l15, q, mg);
    __syncthreads();
    A = An; An = loadA(Wt + 5 * 16384, n0, l15, q);
    mlp_stage<4, false>(A, T1, T0, bb[2], nullptr, n0, l15, q, mg);
    __syncthreads();
    A = An;
    mlp_stage<4, false>(A, T0, T1, bb[2] + 128, nullptr, n0, l15, q, mg);
    __syncthreads();

    // ---- final: out = normalize(T1 @ Wn + bn); 64 rows x 16 cols = 1024 ----
    float* WnS = (float*)T0;                               // 8 KB <= T0
    if (tid < 512) *(float4*)(WnS + tid * 4) = *(const float4*)(P.Wn + tid * 4);
    __syncthreads();
    {
        const int row = tid >> 4, j = tid & 15;
        float acc = P.bn[j];
        const ushort* h = T1 + row * LDST;
#pragma unroll 8
        for (int k = 0; k < 128; ++k) acc += bf2f(h[k]) * WnS[k * 16 + j];
        const float other = __shfl_xor(acc, 8);            // re<->im partner (same wave)
        const float mag = sqrtf(acc * acc + other * other);
        P.out[(size_t)(b * 64 + row) * 16 + j] = acc / mag;
    }
}

extern "C" void kernel_launch(void* const* d_in, const int* in_sizes, int n_in,
                              void* d_out, int out_size, void* d_ws, size_t ws_size,
                              hipStream_t stream)
{
    GP P;
    P.uf    = (const float*)d_in[0];
    P.noise = (const float*)d_in[1];
    const float* W_ue = (const float*)d_in[6];
    P.b_ue  = (const float*)d_in[7];
    P.W_t   = (const float*)d_in[8];
    P.b_t   = (const float*)d_in[9];
    const float* caW[3] = {(const float*)d_in[10], (const float*)d_in[12], (const float*)d_in[14]};
    const float* cab[3] = {(const float*)d_in[11], (const float*)d_in[13], (const float*)d_in[15]};
    const float* cuW[3] = {(const float*)d_in[16], (const float*)d_in[18], (const float*)d_in[20]};
    const float* cub[3] = {(const float*)d_in[17], (const float*)d_in[19], (const float*)d_in[21]};
    P.Wn  = (const float*)d_in[22];
    P.bn  = (const float*)d_in[23];
    P.out = (float*)d_out;

    P.wsrc[0]  = caW[0]; P.wsrc[1]  = caW[0] + 16384;
    P.wsrc[2]  = caW[1]; P.wsrc[3]  = caW[1] + 16384;
    P.wsrc[4]  = caW[2]; P.wsrc[5]  = caW[2] + 16384;
    P.wsrc[6]  = cuW[0]; P.wsrc[7]  = cuW[0] + 16384;
    P.wsrc[8]  = cuW[1]; P.wsrc[9]  = cuW[1] + 16384;
    P.wsrc[10] = cuW[2]; P.wsrc[11] = cuW[2] + 16384;
    P.wsrc[12] = W_ue;
    P.bias6[0] = cab[0]; P.bias6[1] = cab[1]; P.bias6[2] = cab[2];
    P.bias6[3] = cub[0]; P.bias6[4] = cub[1]; P.bias6[5] = cub[2];

    char* w = (char*)d_ws;
    P.cnt   = (unsigned*)w;                     // [0]=prep count, [32]=prep flag
    P.WtAll = (ushort*)(w + 1024);              // 13 * 16384 bf16 (416 KB)

    hipMemsetAsync(w, 0, 1024, stream);         // counters only
    k_gnn<<<dim3(128), dim3(1024), 0, stream>>>(P);
}

// Round 11
// 132.267 us; speedup vs baseline: 1.1283x; 1.1283x over previous
//
#include <hip/hip_runtime.h>
#include <math.h>

// B=128, NU=32, NT=64, H=128, OUT_F=16, N_U=4096, N_A=8192
// Per-batch-local GNN (fully bipartite within batch; segment-means are
// per-batch means). R11 = R10 with the it1 comb prefetch-chain bug fixed
// (was Wm[2]->Wm[4]->Wm[5]->Wm[3]; must be Wm[2]->Wm[3]->Wm[4]->Wm[5]).
//   256 blocks x 512 threads (8 waves, n-split 8): block (b,half) owns
//   16 hu + 32 ha rows in LDS end-to-end.
//   NO weight-prep phase, NO grid barrier: each wave builds its MFMA
//   A-fragments straight from the original fp32 [k][n] weights -- 32 scalar
//   loads of its 16-col slice, prefetched ONE STAGE AHEAD into VGPRs,
//   bf16-converted while the current stage runs. Weight lines are
//   block-shared => L2-resident after first touch.
//   All bias vectors staged to LDS once.
//   Cross-block: 4 colsum partials (sc1 write-through, write-once,
//   first-touch-after-sync) + 3 pairwise seq-flag syncs. Relaxed atomics
//   only; no inv/wbl2 anywhere.

using frag  = __attribute__((ext_vector_type(8))) short;   // 8 x bf16
using f32x4 = __attribute__((ext_vector_type(4))) float;

#define LDST 136
#define SCOPE_AGT __HIP_MEMORY_SCOPE_AGENT

__device__ __forceinline__ float  bf2f(ushort u) { return __uint_as_float(((unsigned)u) << 16); }
__device__ __forceinline__ ushort f2bf(float f) {
    unsigned u = __float_as_uint(f);
    u += 0x7fff + ((u >> 16) & 1);            // RNE
    return (ushort)(u >> 16);
}
__device__ __forceinline__ void gst4_sc(void* p, unsigned v) {   // write-through to MALL
    asm volatile("global_store_dword %0, %1, off sc1" :: "v"(p), "v"(v) : "memory");
}

struct GP {
    const float *uf, *noise, *b_ue, *W_t, *b_t;
    const float *Wm[13];      // fp32 [k][n] weight mats; 12 = W_ue
    const float *bias6[6];
    const float *Wn, *bn;
    float *out;
    float *pE, *pA0, *pU0, *pA1;   // per-block 128-f colsum partials
    unsigned *flg;
};
// Wm slots: 0,1 ca_aggr L0/L1; 2,3 ca_self; 4,5 ca_comb; 6,7 cu_aggr;
//           8,9 cu_self; 10,11 cu_comb; 12 W_ue

// ---- pairwise sync: single-writer seq flags ----
__device__ __forceinline__ void psync(unsigned* myf, unsigned* pf, unsigned s) {
    asm volatile("s_waitcnt vmcnt(0)" ::: "memory");   // drain my sc1 stores
    __syncthreads();
    if (threadIdx.x == 0) {
        __hip_atomic_store(myf, s, __ATOMIC_RELAXED, SCOPE_AGT);
        while (__hip_atomic_load(pf, __ATOMIC_RELAXED, SCOPE_AGT) < s)
            __builtin_amdgcn_s_sleep(1);
    }
    __syncthreads();
}

// ---- A-fragment pipeline: 32 fp32 loads (one stage ahead) -> bf16 frags ----
struct PF { float v[32]; };
struct AF { frag f[4]; };
__device__ __forceinline__ PF prefA(const float* __restrict__ W, int n0, int l15, int q) {
    PF p;
    const float* base = W + (size_t)(q * 8) * 128 + n0 + l15;
#pragma unroll
    for (int kc = 0; kc < 4; ++kc)
#pragma unroll
        for (int j = 0; j < 8; ++j)
            p.v[kc * 8 + j] = base[(kc * 32 + j) * 128];   // W[(kc*32+q*8+j)][n0+l15]
    return p;
}
__device__ __forceinline__ AF convA(const PF& p) {
    AF a;
#pragma unroll
    for (int kc = 0; kc < 4; ++kc) {
        frag f;
#pragma unroll
        for (int j = 0; j < 8; ++j) f[j] = (short)f2bf(p.v[kc * 8 + j]);
        a.f[kc] = f;
    }
    return a;
}

// ---- MLP stage: wave w owns n-cols [16w,16w+16); MT m-tiles; LDS bias ----
template<int MT, bool MEANADD>
__device__ __forceinline__ void mlp_stage(const AF& A, const ushort* Xl, ushort* Yl,
    const float* biasL, const float* meanL, int n0, int l15, int q)
{
    const float4 bv = *(const float4*)(biasL + n0 + q * 4);
    float4 mv = {0.f, 0.f, 0.f, 0.f};
    if (MEANADD) mv = *(const float4*)(meanL + n0 + q * 4);
#pragma unroll
    for (int mt = 0; mt < MT; ++mt) {
        frag Bv[4];
#pragma unroll
        for (int kc = 0; kc < 4; ++kc)
            Bv[kc] = *(const frag*)(Xl + (mt * 16 + l15) * LDST + kc * 32 + q * 8);
        f32x4 acc = {0.f, 0.f, 0.f, 0.f};
#pragma unroll
        for (int kc = 0; kc < 4; ++kc)
            acc = __builtin_amdgcn_mfma_f32_16x16x32_bf16(A.f[kc], Bv[kc], acc, 0, 0, 0);
        float v0 = acc[0] + bv.x, v1 = acc[1] + bv.y, v2 = acc[2] + bv.z, v3 = acc[3] + bv.w;
        v0 = v0 > 0.f ? v0 : 0.f; v1 = v1 > 0.f ? v1 : 0.f;
        v2 = v2 > 0.f ? v2 : 0.f; v3 = v3 > 0.f ? v3 : 0.f;
        if (MEANADD) { v0 += mv.x; v1 += mv.y; v2 += mv.z; v3 += mv.w; }
        ushort4 o = { f2bf(v0), f2bf(v1), f2bf(v2), f2bf(v3) };
        *(ushort4*)(Yl + (mt * 16 + l15) * LDST + n0 + q * 4) = o;
    }
}

// ---- column sum over ROWS rows -> own LDS dst + sc1 global partial ----
template<int ROWS>
__device__ __forceinline__ void colsum(const ushort* buf, float* redL,
                                       float* ownDst, float* __restrict__ gDst)
{
    const int t = threadIdx.x, g = t >> 7, col = t & 127;
    float s = 0.f;
#pragma unroll
    for (int r = g; r < ROWS; r += 4) s += bf2f(buf[r * LDST + col]);
    redL[g * 128 + col] = s;
    __syncthreads();
    if (t < 128) {
        float tot = redL[t] + redL[128 + t] + redL[256 + t] + redL[384 + t];
        ownDst[t] = tot;
        gst4_sc(gDst + t, __float_as_uint(tot));
    }
    __syncthreads();
}

__global__ __launch_bounds__(512, 1) void k_gnn(GP P)
{
    __shared__ __align__(16) ushort HU[16 * LDST];   // hu -> (aliased) hu2
    __shared__ __align__(16) ushort HA[32 * LDST];   // ha -> (aliased) ha2
    __shared__ __align__(16) ushort T0[32 * LDST];
    __shared__ __align__(16) ushort T1[32 * LDST];
    __shared__ __align__(16) float  biasL[1792];     // all bias vectors
    __shared__ __align__(16) float  redL[512];
    __shared__ __align__(16) float  meanP[128], meanQ[128], antL[128];

    const int blk = blockIdx.x, tid = threadIdx.x;
    const int b = blk >> 1, half = blk & 1, prt = blk ^ 1;
    const int lane = tid & 63, wave = tid >> 6;
    const int q = lane >> 4, l15 = lane & 15;
    const int n0 = wave * 16;
    unsigned* myf = P.flg + blk * 32;
    unsigned* prf = P.flg + prt * 32;

    // ---- first A prefetch (embed weights), then stage inputs ----
    PF p = prefA(P.Wm[12], n0, l15, q);

    {   // 16 uf rows -> T0 (512 float4 chunks exactly)
        const int r = tid >> 5, k4 = tid & 31;
        const float4 v = *(const float4*)(P.uf + (size_t)(b * 32 + half * 16 + r) * 128 + k4 * 4);
        ushort4 o = { f2bf(v.x), f2bf(v.y), f2bf(v.z), f2bf(v.w) };
        *(ushort4*)(T0 + r * LDST + k4 * 4) = o;
    }
#pragma unroll
    for (int c = tid; c < 1024; c += 512) {   // 32 noise rows -> HA (ant added later)
        const int r = c >> 5, k4 = c & 31;
        const float4 v = *(const float4*)(P.noise + (size_t)(b * 64 + half * 32 + r) * 128 + k4 * 4);
        ushort4 o = { f2bf(v.x), f2bf(v.y), f2bf(v.z), f2bf(v.w) };
        *(ushort4*)(HA + r * LDST + k4 * 4) = o;
    }
    // bias vectors -> LDS (once)
    if (tid < 128) biasL[tid] = P.b_ue[tid];
    if (tid < 128) biasL[1664 + tid] = P.b_t[tid];
#pragma unroll
    for (int r = 0; r < 6; ++r)
        if (tid < 256) biasL[128 + r * 256 + tid] = P.bias6[r][tid];
    __syncthreads();

    AF A;
    // S1 embed: T0 -> HU
    A = convA(p); p = prefA(P.Wm[0], n0, l15, q);
    mlp_stage<1, false>(A, T0, HU, biasL + 0, nullptr, n0, l15, q);
    __syncthreads();
    colsum<16>(HU, redL, meanP, P.pE + blk * 128);          // E partial
    // S2-S3 it0 aggr-hu
    A = convA(p); p = prefA(P.Wm[1], n0, l15, q);
    mlp_stage<1, false>(A, HU, T0, biasL + 128, nullptr, n0, l15, q);
    __syncthreads();
    A = convA(p); p = prefA(P.Wm[6], n0, l15, q);
    mlp_stage<1, false>(A, T0, T1, biasL + 256, nullptr, n0, l15, q);
    __syncthreads();
    colsum<16>(T1, redL, meanQ, P.pA0 + blk * 128);         // A0 partial
    psync(myf, prf, 1u);

    // ant = relu(meanE @ W_t + b_t); HA += ant ; combine meanQ (A0) too
    if (tid < 128) {
        meanP[tid] = (meanP[tid] + P.pE[prt * 128 + tid]) * (1.f / 32.f);
        meanQ[tid] = (meanQ[tid] + P.pA0[prt * 128 + tid]) * (1.f / 32.f);
    }
    __syncthreads();
    {
        const int g = tid >> 7, col = tid & 127;
        float s = 0.f;
#pragma unroll 4
        for (int k = g * 32; k < g * 32 + 32; ++k) s += meanP[k] * P.W_t[k * 128 + col];
        redL[g * 128 + col] = s;
    }
    __syncthreads();
    if (tid < 128) {
        float a = biasL[1664 + tid] + redL[tid] + redL[128 + tid] + redL[256 + tid] + redL[384 + tid];
        antL[tid] = a > 0.f ? a : 0.f;
    }
    __syncthreads();
#pragma unroll
    for (int c = tid; c < 1024; c += 512) {
        const int r = c >> 5, k4 = c & 31;
        ushort4 h = *(ushort4*)(HA + r * LDST + k4 * 4);
        ushort4 o = { f2bf(bf2f(h.x) + antL[k4 * 4 + 0]), f2bf(bf2f(h.y) + antL[k4 * 4 + 1]),
                      f2bf(bf2f(h.z) + antL[k4 * 4 + 2]), f2bf(bf2f(h.w) + antL[k4 * 4 + 3]) };
        *(ushort4*)(HA + r * LDST + k4 * 4) = o;
    }
    __syncthreads();

    // S4-S5 it0 aggr-ha
    A = convA(p); p = prefA(P.Wm[7], n0, l15, q);
    mlp_stage<2, false>(A, HA, T0, biasL + 896, nullptr, n0, l15, q);
    __syncthreads();
    A = convA(p); p = prefA(P.Wm[2], n0, l15, q);
    mlp_stage<2, false>(A, T0, T1, biasL + 1024, nullptr, n0, l15, q);
    __syncthreads();
    colsum<32>(T1, redL, meanP, P.pU0 + blk * 128);         // U0 partial
    // S6 self-ha L0 (independent of partner -> overlap psync2)
    A = convA(p); p = prefA(P.Wm[3], n0, l15, q);
    mlp_stage<2, false>(A, HA, T0, biasL + 384, nullptr, n0, l15, q);
    __syncthreads();
    psync(myf, prf, 2u);
    if (tid < 128)
        meanP[tid] = (meanP[tid] + P.pU0[prt * 128 + tid]) * (1.f / 64.f);
    __syncthreads();
    // S7-S9 it0 comb-ha ; HA := ha2
    A = convA(p); p = prefA(P.Wm[4], n0, l15, q);
    mlp_stage<2, true >(A, T0, T1, biasL + 512, meanQ, n0, l15, q);
    __syncthreads();
    A = convA(p); p = prefA(P.Wm[5], n0, l15, q);
    mlp_stage<2, false>(A, T1, T0, biasL + 640, nullptr, n0, l15, q);
    __syncthreads();
    A = convA(p); p = prefA(P.Wm[8], n0, l15, q);
    mlp_stage<2, false>(A, T0, HA, biasL + 768, nullptr, n0, l15, q);
    __syncthreads();
    // S10-S13 it0 comb-hu ; HU := hu2
    A = convA(p); p = prefA(P.Wm[9], n0, l15, q);
    mlp_stage<1, false>(A, HU, T0, biasL + 1152, nullptr, n0, l15, q);
    __syncthreads();
    A = convA(p); p = prefA(P.Wm[10], n0, l15, q);
    mlp_stage<1, true >(A, T0, T1, biasL + 1280, meanP, n0, l15, q);
    __syncthreads();
    A = convA(p); p = prefA(P.Wm[11], n0, l15, q);
    mlp_stage<1, false>(A, T1, T0, biasL + 1408, nullptr, n0, l15, q);
    __syncthreads();
    A = convA(p); p = prefA(P.Wm[0], n0, l15, q);
    mlp_stage<1, false>(A, T0, HU, biasL + 1536, nullptr, n0, l15, q);
    __syncthreads();

    // S14-S15 it1 aggr-hu2 (it1 cu-side is dead)
    A = convA(p); p = prefA(P.Wm[1], n0, l15, q);
    mlp_stage<1, false>(A, HU, T0, biasL + 128, nullptr, n0, l15, q);
    __syncthreads();
    A = convA(p); p = prefA(P.Wm[2], n0, l15, q);
    mlp_stage<1, false>(A, T0, T1, biasL + 256, nullptr, n0, l15, q);
    __syncthreads();
    colsum<16>(T1, redL, meanQ, P.pA1 + blk * 128);         // A1 partial
    // S16 self-ha2 L0 (overlap psync3)      [R11 FIX: prefetch Wm[3], not Wm[4]]
    A = convA(p); p = prefA(P.Wm[3], n0, l15, q);
    mlp_stage<2, false>(A, HA, T0, biasL + 384, nullptr, n0, l15, q);
    __syncthreads();
    psync(myf, prf, 3u);
    if (tid < 128)
        meanQ[tid] = (meanQ[tid] + P.pA1[prt * 128 + tid]) * (1.f / 32.f);
    __syncthreads();
    // S17-S19 it1 comb-ha2 -> T1   [R11 FIX: chain Wm[3] -> Wm[4] -> Wm[5]]
    A = convA(p); p = prefA(P.Wm[4], n0, l15, q);
    mlp_stage<2, true >(A, T0, T1, biasL + 512, meanQ, n0, l15, q);
    __syncthreads();
    A = convA(p); p = prefA(P.Wm[5], n0, l15, q);
    mlp_stage<2, false>(A, T1, T0, biasL + 640, nullptr, n0, l15, q);
    __syncthreads();
    A = convA(p);
    mlp_stage<2, false>(A, T0, T1, biasL + 768, nullptr, n0, l15, q);
    __syncthreads();

    // ---- final: out = normalize(T1 @ Wn + bn); 32 rows x 16 cols = 512 ----
    float* WnS = (float*)T0;                               // 8 KB <= T0
    *(float4*)(WnS + tid * 4) = *(const float4*)(P.Wn + tid * 4);
    __syncthreads();
    {
        const int row = tid >> 4, j = tid & 15;
        float acc = P.bn[j];
        const ushort* h = T1 + row * LDST;
#pragma unroll 8
        for (int k = 0; k < 128; ++k) acc += bf2f(h[k]) * WnS[k * 16 + j];
        const float other = __shfl_xor(acc, 8);            // re<->im partner, same wave
        const float mag = sqrtf(acc * acc + other * other);
        P.out[(size_t)(b * 64 + half * 32 + row) * 16 + j] = acc / mag;
    }
}

extern "C" void kernel_launch(void* const* d_in, const int* in_sizes, int n_in,
                              void* d_out, int out_size, void* d_ws, size_t ws_size,
                              hipStream_t stream)
{
    GP P;
    P.uf    = (const float*)d_in[0];
    P.noise = (const float*)d_in[1];
    const float* W_ue = (const float*)d_in[6];
    P.b_ue  = (const float*)d_in[7];
    P.W_t   = (const float*)d_in[8];
    P.b_t   = (const float*)d_in[9];
    const float* caW[3] = {(const float*)d_in[10], (const float*)d_in[12], (const float*)d_in[14]};
    const float* cab[3] = {(const float*)d_in[11], (const float*)d_in[13], (const float*)d_in[15]};
    const float* cuW[3] = {(const float*)d_in[16], (const float*)d_in[18], (const float*)d_in[20]};
    const float* cub[3] = {(const float*)d_in[17], (const float*)d_in[19], (const float*)d_in[21]};
    P.Wn  = (const float*)d_in[22];
    P.bn  = (const float*)d_in[23];
    P.out = (float*)d_out;

    P.Wm[0]  = caW[0]; P.Wm[1]  = caW[0] + 16384;
    P.Wm[2]  = caW[1]; P.Wm[3]  = caW[1] + 16384;
    P.Wm[4]  = caW[2]; P.Wm[5]  = caW[2] + 16384;
    P.Wm[6]  = cuW[0]; P.Wm[7]  = cuW[0] + 16384;
    P.Wm[8]  = cuW[1]; P.Wm[9]  = cuW[1] + 16384;
    P.Wm[10] = cuW[2]; P.Wm[11] = cuW[2] + 16384;
    P.Wm[12] = W_ue;
    P.bias6[0] = cab[0]; P.bias6[1] = cab[1]; P.bias6[2] = cab[2];
    P.bias6[3] = cub[0]; P.bias6[4] = cub[1]; P.bias6[5] = cub[2];

    char* w = (char*)d_ws;
    P.flg = (unsigned*)w;                       // 256 flags, 128 B apart (32 KB)
    P.pE  = (float*)(w + 32768);                // 4 partial arrays, 256*128 f each
    P.pA0 = P.pE  + 256 * 128;
    P.pU0 = P.pA0 + 256 * 128;
    P.pA1 = P.pU0 + 256 * 128;

    hipMemsetAsync(w, 0, 32768, stream);        // flags only
    k_gnn<<<dim3(256), dim3(512), 0, stream>>>(P);
}